// Round 5
// baseline (227.228 us; speedup 1.0000x reference)
//
#include <hip/hip_runtime.h>

#define NB 8192
#define NPTS 1024
#define NBLK 2048
#define TPB 128                      // 2 waves/block; 4096 waves x 2 batches each

// Output layout (flat concat, float32):
//   R: [0, NB*9)      t: [NB*9, NB*12)      S: [NB*12, NB*13)
//
// Persistent-stream design: each wave owns 2 consecutive batches (48 KiB
// contiguous). 8 chunk-slots (2 batches x 4 chunks), register double-buffer:
// slot s+1's 6 dwordx4 loads are issued BEFORE slot s is consumed, keeping
// VMEM saturated across the per-batch butterfly+polar gap. No LDS, no
// barriers; butterfly leaves the full sums in every lane, so the polar
// Newton chain runs redundantly on all 64 lanes (VALU) while the next
// batch's loads are in flight (VMEM).
__global__ __launch_bounds__(TPB) void fused_kernel(
    const float* __restrict__ x, const float* __restrict__ y,
    const float* __restrict__ mu_x, const float* __restrict__ mu_y,
    float* __restrict__ out)
{
    const int lane = threadIdx.x & 63;
    const int wid  = blockIdx.x * (TPB / 64) + (threadIdx.x >> 6);   // 0..4095
    const int b0   = wid * 2;                                        // batches b0, b0+1

    float4 bx[2][3], by[2][3];      // double-buffered chunk registers

    // mu for the current batch (wave-uniform values, reloaded per batch)
    float mx0 = mu_x[b0 * 3 + 0], mx1 = mu_x[b0 * 3 + 1], mx2 = mu_x[b0 * 3 + 2];
    float my0 = mu_y[b0 * 3 + 0], my1 = mu_y[b0 * 3 + 1], my2 = mu_y[b0 * 3 + 2];

    // issue slot 0 (batch b0, chunk 0)
    {
        const float4* x4 = (const float4*)(x + (size_t)b0 * (NPTS * 3));
        const float4* y4 = (const float4*)(y + (size_t)b0 * (NPTS * 3));
        const int base = 3 * lane;
        bx[0][0] = x4[base + 0]; bx[0][1] = x4[base + 1]; bx[0][2] = x4[base + 2];
        by[0][0] = y4[base + 0]; by[0][1] = y4[base + 1]; by[0][2] = y4[base + 2];
    }

    float v[11];
    #pragma unroll
    for (int i = 0; i < 11; ++i) v[i] = 0.0f;

    #pragma unroll
    for (int s = 0; s < 8; ++s) {
        // ---- prefetch slot s+1 into the other buffer ----
        if (s < 7) {
            const int b = b0 + ((s + 1) >> 2);
            const int c = (s + 1) & 3;
            const float4* x4 = (const float4*)(x + (size_t)b * (NPTS * 3));
            const float4* y4 = (const float4*)(y + (size_t)b * (NPTS * 3));
            const int base = 3 * (c * 64 + lane);
            const int sl = (s + 1) & 1;
            bx[sl][0] = x4[base + 0]; bx[sl][1] = x4[base + 1]; bx[sl][2] = x4[base + 2];
            by[sl][0] = y4[base + 0]; by[sl][1] = y4[base + 1]; by[sl][2] = y4[base + 2];
        }

        // ---- consume slot s ----
        const int sl = s & 1;
        const float4 xa = bx[sl][0], xb4 = bx[sl][1], xc4 = bx[sl][2];
        const float4 ya = by[sl][0], yb4 = by[sl][1], yc4 = by[sl][2];

        const float xp[4][3] = {{xa.x, xa.y, xa.z}, {xa.w, xb4.x, xb4.y},
                                {xb4.z, xb4.w, xc4.x}, {xc4.y, xc4.z, xc4.w}};
        const float yp[4][3] = {{ya.x, ya.y, ya.z}, {ya.w, yb4.x, yb4.y},
                                {yb4.z, yb4.w, yc4.x}, {yc4.y, yc4.z, yc4.w}};

        #pragma unroll
        for (int k = 0; k < 4; ++k) {
            const float xd0 = xp[k][0] - mx0, xd1 = xp[k][1] - mx1, xd2 = xp[k][2] - mx2;
            const float yd0 = yp[k][0] - my0, yd1 = yp[k][1] - my1, yd2 = yp[k][2] - my2;
            v[0] += xd0 * yd0; v[1] += xd0 * yd1; v[2] += xd0 * yd2;
            v[3] += xd1 * yd0; v[4] += xd1 * yd1; v[5] += xd1 * yd2;
            v[6] += xd2 * yd0; v[7] += xd2 * yd1; v[8] += xd2 * yd2;
            v[9]  += xd0 * xd0 + xd1 * xd1 + xd2 * xd2;
            v[10] += yd0 * yd0 + yd1 * yd1 + yd2 * yd2;
        }

        // ---- batch finished: reduce + polar + write, overlapped with the
        //      already-in-flight loads of the next batch's chunk 0 ----
        if ((s & 3) == 3) {
            const int b = b0 + (s >> 2);

            // 64-lane butterfly: every lane ends with the full batch sums.
            #pragma unroll
            for (int off = 32; off >= 1; off >>= 1) {
                #pragma unroll
                for (int i = 0; i < 11; ++i) v[i] += __shfl_xor(v[i], off, 64);
            }

            float Q[9] = {v[0], v[1], v[2], v[3], v[4], v[5], v[6], v[7], v[8]};
            const float nxx = v[9];
            const float nyy = v[10];

            // Scaled Newton polar factor (redundant on all 64 lanes):
            //   Q <- 0.5 * (g*Q + (1/g) * Q^-T), g = sqrt(||Q^-1||_F/||Q||_F)
            // Raw-rate v_rcp/v_sqrt: iteration is self-correcting.
            #pragma unroll
            for (int it = 0; it < 11; ++it) {
                float C[9];
                C[0] = Q[4] * Q[8] - Q[5] * Q[7];
                C[1] = Q[5] * Q[6] - Q[3] * Q[8];
                C[2] = Q[3] * Q[7] - Q[4] * Q[6];
                C[3] = Q[2] * Q[7] - Q[1] * Q[8];
                C[4] = Q[0] * Q[8] - Q[2] * Q[6];
                C[5] = Q[1] * Q[6] - Q[0] * Q[7];
                C[6] = Q[1] * Q[5] - Q[2] * Q[4];
                C[7] = Q[2] * Q[3] - Q[0] * Q[5];
                C[8] = Q[0] * Q[4] - Q[1] * Q[3];
                const float det = Q[0] * C[0] + Q[1] * C[1] + Q[2] * C[2];
                const float invdet = __builtin_amdgcn_rcpf(det);

                float nq = 0.0f, nc = 0.0f;
                #pragma unroll
                for (int i = 0; i < 9; ++i) { nq += Q[i] * Q[i]; nc += C[i] * C[i]; }
                const float g  = __builtin_amdgcn_sqrtf(__builtin_amdgcn_sqrtf(
                                     nc * invdet * invdet * __builtin_amdgcn_rcpf(nq)));
                const float hg = 0.5f * g;
                const float hi = 0.5f * invdet * __builtin_amdgcn_rcpf(g);
                #pragma unroll
                for (int i = 0; i < 9; ++i) Q[i] = hg * Q[i] + hi * C[i];
            }

            if (lane == 0) {
                #pragma unroll
                for (int i = 0; i < 9; ++i) out[(size_t)b * 9 + i] = Q[i];

                float* tout = out + (size_t)NB * 9 + (size_t)b * 3;
                tout[0] = my0 - (Q[0] * mx0 + Q[1] * mx1 + Q[2] * mx2);
                tout[1] = my1 - (Q[3] * mx0 + Q[4] * mx1 + Q[5] * mx2);
                tout[2] = my2 - (Q[6] * mx0 + Q[7] * mx1 + Q[8] * mx2);

                out[(size_t)NB * 12 + b] =
                    __builtin_amdgcn_sqrtf(nyy) / (__builtin_amdgcn_sqrtf(nxx) + 1e-6f);
            }

            // reset accumulators and advance mu to the next batch
            #pragma unroll
            for (int i = 0; i < 11; ++i) v[i] = 0.0f;
            if (s < 7) {
                const int bn = b + 1;
                mx0 = mu_x[bn * 3 + 0]; mx1 = mu_x[bn * 3 + 1]; mx2 = mu_x[bn * 3 + 2];
                my0 = mu_y[bn * 3 + 0]; my1 = mu_y[bn * 3 + 1]; my2 = mu_y[bn * 3 + 2];
            }
        }
    }
}

extern "C" void kernel_launch(void* const* d_in, const int* in_sizes, int n_in,
                              void* d_out, int out_size, void* d_ws, size_t ws_size,
                              hipStream_t stream) {
    const float* x    = (const float*)d_in[0];
    const float* mu_x = (const float*)d_in[1];
    const float* y    = (const float*)d_in[2];
    const float* mu_y = (const float*)d_in[3];
    float* out = (float*)d_out;
    (void)d_ws; (void)ws_size;

    fused_kernel<<<dim3(NBLK), dim3(TPB), 0, stream>>>(x, y, mu_x, mu_y, out);
}

// Round 6
// 219.770 us; speedup vs baseline: 1.0339x; 1.0339x over previous
//
#include <hip/hip_runtime.h>

#define NB 8192
#define NPTS 1024

// Output layout (flat concat, float32):
//   R: [0, NB*9)      t: [NB*9, NB*12)      S: [NB*12, NB*13)
//
// Workspace: ws[b*12 + 0..8] = cov (row-major), ws[b*12+9] = |xc|^2,
//            ws[b*12+10] = |yc|^2, [11] = pad.
//
// Round-6 experiment: REVERSE batch order (b = NB-1-blockIdx).
// Evidence (rounds 0-5): dur == FETCH_SIZE / ~1.3 TB/s for every structure;
// ~half the 201 MB input is L3-resident at kernel start (the harness restore
// pass's most-recently-written tail). Forward order reads the cold front
// first and self-evicts the hot tail with its own miss fills. Reverse order
// consumes the hot tail first, then the cold (contiguous -> DRAM-friendly)
// front. Everything else is identical to the 77-us round-3 kernel for a
// clean A/B.
__global__ __launch_bounds__(256) void cov_kernel(
    const float* __restrict__ x, const float* __restrict__ y,
    const float* __restrict__ mu_x, const float* __restrict__ mu_y,
    float* __restrict__ ws)
{
    __shared__ float4 sx[768];          // 12 KiB: one batch of x
    __shared__ float4 sy[768];          // 12 KiB: one batch of y
    __shared__ float red[4][12];        // cross-wave partials

    const int t = threadIdx.x;
    const int b = NB - 1 - blockIdx.x;  // <<< the experiment

    const float4* x4 = (const float4*)(x + (size_t)b * (NPTS * 3));
    const float4* y4 = (const float4*)(y + (size_t)b * (NPTS * 3));

    // Coalesced stage: instruction j has lanes covering float4 [256j, 256j+256).
    const float4 a0 = x4[t], a1 = x4[t + 256], a2 = x4[t + 512];
    const float4 c0 = y4[t], c1 = y4[t + 256], c2 = y4[t + 512];

    const float mx0 = mu_x[b * 3 + 0], mx1 = mu_x[b * 3 + 1], mx2 = mu_x[b * 3 + 2];
    const float my0 = mu_y[b * 3 + 0], my1 = mu_y[b * 3 + 1], my2 = mu_y[b * 3 + 2];

    sx[t] = a0; sx[t + 256] = a1; sx[t + 512] = a2;
    sy[t] = c0; sy[t + 256] = c1; sy[t + 512] = c2;
    __syncthreads();

    // Thread t owns points 4t..4t+3 -> float4 indices 3t..3t+2.
    const float4 xa = sx[3 * t + 0], xb4 = sx[3 * t + 1], xc4 = sx[3 * t + 2];
    const float4 ya = sy[3 * t + 0], yb4 = sy[3 * t + 1], yc4 = sy[3 * t + 2];

    const float xp[4][3] = {{xa.x, xa.y, xa.z}, {xa.w, xb4.x, xb4.y},
                            {xb4.z, xb4.w, xc4.x}, {xc4.y, xc4.z, xc4.w}};
    const float yp[4][3] = {{ya.x, ya.y, ya.z}, {ya.w, yb4.x, yb4.y},
                            {yb4.z, yb4.w, yc4.x}, {yc4.y, yc4.z, yc4.w}};

    float v[11];
    #pragma unroll
    for (int i = 0; i < 11; ++i) v[i] = 0.0f;

    #pragma unroll
    for (int k = 0; k < 4; ++k) {
        const float xd0 = xp[k][0] - mx0, xd1 = xp[k][1] - mx1, xd2 = xp[k][2] - mx2;
        const float yd0 = yp[k][0] - my0, yd1 = yp[k][1] - my1, yd2 = yp[k][2] - my2;
        v[0] += xd0 * yd0; v[1] += xd0 * yd1; v[2] += xd0 * yd2;
        v[3] += xd1 * yd0; v[4] += xd1 * yd1; v[5] += xd1 * yd2;
        v[6] += xd2 * yd0; v[7] += xd2 * yd1; v[8] += xd2 * yd2;
        v[9]  += xd0 * xd0 + xd1 * xd1 + xd2 * xd2;
        v[10] += yd0 * yd0 + yd1 * yd1 + yd2 * yd2;
    }

    // 64-lane butterfly per wave.
    #pragma unroll
    for (int off = 32; off >= 1; off >>= 1) {
        #pragma unroll
        for (int i = 0; i < 11; ++i) v[i] += __shfl_xor(v[i], off, 64);
    }

    if ((t & 63) == 0) {
        #pragma unroll
        for (int i = 0; i < 11; ++i) red[t >> 6][i] = v[i];
    }
    __syncthreads();

    if (t < 11) {
        ws[(size_t)b * 12 + t] = red[0][t] + red[1][t] + red[2][t] + red[3][t];
    }
}

// ---------------- Kernel B: per-thread polar factor + epilogue ----------------
// One batch per thread; raw-rate v_rcp_f32 / v_sqrt_f32 (Newton iteration is
// self-correcting) cut the dependent critical path ~2.5x vs IEEE sequences.
__global__ __launch_bounds__(256) void polar_kernel(
    const float* __restrict__ ws,
    const float* __restrict__ mu_x, const float* __restrict__ mu_y,
    float* __restrict__ out)
{
    const int b = blockIdx.x * 256 + threadIdx.x;

    const float4* w4 = (const float4*)ws + 3 * (size_t)b;
    const float4 w0 = w4[0], w1 = w4[1], w2 = w4[2];

    float Q[9] = {w0.x, w0.y, w0.z, w0.w, w1.x, w1.y, w1.z, w1.w, w2.x};
    const float nxx = w2.y;   // |xc|^2
    const float nyy = w2.z;   // |yc|^2

    // Scaled Newton iteration for the orthogonal polar factor:
    //   Q <- 0.5 * (g*Q + (1/g) * Q^-T),  g = sqrt(||Q^-1||_F / ||Q||_F)
    #pragma unroll
    for (int it = 0; it < 11; ++it) {
        float C[9];
        C[0] = Q[4] * Q[8] - Q[5] * Q[7];
        C[1] = Q[5] * Q[6] - Q[3] * Q[8];
        C[2] = Q[3] * Q[7] - Q[4] * Q[6];
        C[3] = Q[2] * Q[7] - Q[1] * Q[8];
        C[4] = Q[0] * Q[8] - Q[2] * Q[6];
        C[5] = Q[1] * Q[6] - Q[0] * Q[7];
        C[6] = Q[1] * Q[5] - Q[2] * Q[4];
        C[7] = Q[2] * Q[3] - Q[0] * Q[5];
        C[8] = Q[0] * Q[4] - Q[1] * Q[3];
        const float det = Q[0] * C[0] + Q[1] * C[1] + Q[2] * C[2];
        const float invdet = __builtin_amdgcn_rcpf(det);

        float nq = 0.0f, nc = 0.0f;
        #pragma unroll
        for (int i = 0; i < 9; ++i) { nq += Q[i] * Q[i]; nc += C[i] * C[i]; }
        const float g  = __builtin_amdgcn_sqrtf(__builtin_amdgcn_sqrtf(
                             nc * invdet * invdet * __builtin_amdgcn_rcpf(nq)));
        const float hg = 0.5f * g;
        const float hi = 0.5f * invdet * __builtin_amdgcn_rcpf(g);
        #pragma unroll
        for (int i = 0; i < 9; ++i) Q[i] = hg * Q[i] + hi * C[i];
    }

    const float mx0 = mu_x[b * 3 + 0], mx1 = mu_x[b * 3 + 1], mx2 = mu_x[b * 3 + 2];
    const float my0 = mu_y[b * 3 + 0], my1 = mu_y[b * 3 + 1], my2 = mu_y[b * 3 + 2];

    #pragma unroll
    for (int i = 0; i < 9; ++i) out[(size_t)b * 9 + i] = Q[i];

    float* tout = out + (size_t)NB * 9 + (size_t)b * 3;
    tout[0] = my0 - (Q[0] * mx0 + Q[1] * mx1 + Q[2] * mx2);
    tout[1] = my1 - (Q[3] * mx0 + Q[4] * mx1 + Q[5] * mx2);
    tout[2] = my2 - (Q[6] * mx0 + Q[7] * mx1 + Q[8] * mx2);

    out[(size_t)NB * 12 + b] =
        __builtin_amdgcn_sqrtf(nyy) / (__builtin_amdgcn_sqrtf(nxx) + 1e-6f);
}

extern "C" void kernel_launch(void* const* d_in, const int* in_sizes, int n_in,
                              void* d_out, int out_size, void* d_ws, size_t ws_size,
                              hipStream_t stream) {
    const float* x    = (const float*)d_in[0];
    const float* mu_x = (const float*)d_in[1];
    const float* y    = (const float*)d_in[2];
    const float* mu_y = (const float*)d_in[3];
    float* out = (float*)d_out;
    float* ws  = (float*)d_ws;   // needs NB*12*4 = 384 KiB

    cov_kernel<<<dim3(NB), dim3(256), 0, stream>>>(x, y, mu_x, mu_y, ws);
    polar_kernel<<<dim3(NB / 256), dim3(256), 0, stream>>>(ws, mu_x, mu_y, out);
}

// Round 7
// 202.960 us; speedup vs baseline: 1.1196x; 1.0828x over previous
//
#include <hip/hip_runtime.h>

#define NB 8192
#define NPTS 1024

typedef float vf4 __attribute__((ext_vector_type(4)));

// Output layout (flat concat, float32):
//   R: [0, NB*9)      t: [NB*9, NB*12)      S: [NB*12, NB*13)
//
// Workspace: ws[b*12 + 0..8] = cov, ws[b*12+9] = |xc|^2, [10] = |yc|^2.
//
// Round-7 experiment: NON-TEMPORAL loads for all x/y reads (nt bit).
// Evidence through r6: FETCH is pinned at ~one array (~100 MB cold, other
// array L3-hot) and duration is pinned at FETCH/1.3 TB/s across four
// structurally disjoint kernels (no pipe >42%). Remaining kernel-side
// mechanism: TCC allocate+evict churn from the ~50% hit/miss interleave.
// nt loads make misses forward-only (no L3 allocation, no eviction) while
// leaving y's hits untouched; all data is single-use so there is no reuse
// downside. Everything else identical to the 77-us r3/r6 kernel (A/B).
__global__ __launch_bounds__(256) void cov_kernel(
    const float* __restrict__ x, const float* __restrict__ y,
    const float* __restrict__ mu_x, const float* __restrict__ mu_y,
    float* __restrict__ ws)
{
    __shared__ vf4 sx[768];             // 12 KiB: one batch of x
    __shared__ vf4 sy[768];             // 12 KiB: one batch of y
    __shared__ float red[4][12];        // cross-wave partials

    const int t = threadIdx.x;
    const int b = blockIdx.x;

    const vf4* x4 = (const vf4*)(x + (size_t)b * (NPTS * 3));
    const vf4* y4 = (const vf4*)(y + (size_t)b * (NPTS * 3));

    // Coalesced stage, non-temporal: misses bypass L3 allocation.
    const vf4 a0 = __builtin_nontemporal_load(x4 + t);
    const vf4 a1 = __builtin_nontemporal_load(x4 + t + 256);
    const vf4 a2 = __builtin_nontemporal_load(x4 + t + 512);
    const vf4 c0 = __builtin_nontemporal_load(y4 + t);
    const vf4 c1 = __builtin_nontemporal_load(y4 + t + 256);
    const vf4 c2 = __builtin_nontemporal_load(y4 + t + 512);

    const float mx0 = mu_x[b * 3 + 0], mx1 = mu_x[b * 3 + 1], mx2 = mu_x[b * 3 + 2];
    const float my0 = mu_y[b * 3 + 0], my1 = mu_y[b * 3 + 1], my2 = mu_y[b * 3 + 2];

    sx[t] = a0; sx[t + 256] = a1; sx[t + 512] = a2;
    sy[t] = c0; sy[t + 256] = c1; sy[t + 512] = c2;
    __syncthreads();

    // Thread t owns points 4t..4t+3 -> float4 indices 3t..3t+2.
    const vf4 xa = sx[3 * t + 0], xb4 = sx[3 * t + 1], xc4 = sx[3 * t + 2];
    const vf4 ya = sy[3 * t + 0], yb4 = sy[3 * t + 1], yc4 = sy[3 * t + 2];

    const float xp[4][3] = {{xa.x, xa.y, xa.z}, {xa.w, xb4.x, xb4.y},
                            {xb4.z, xb4.w, xc4.x}, {xc4.y, xc4.z, xc4.w}};
    const float yp[4][3] = {{ya.x, ya.y, ya.z}, {ya.w, yb4.x, yb4.y},
                            {yb4.z, yb4.w, yc4.x}, {yc4.y, yc4.z, yc4.w}};

    float v[11];
    #pragma unroll
    for (int i = 0; i < 11; ++i) v[i] = 0.0f;

    #pragma unroll
    for (int k = 0; k < 4; ++k) {
        const float xd0 = xp[k][0] - mx0, xd1 = xp[k][1] - mx1, xd2 = xp[k][2] - mx2;
        const float yd0 = yp[k][0] - my0, yd1 = yp[k][1] - my1, yd2 = yp[k][2] - my2;
        v[0] += xd0 * yd0; v[1] += xd0 * yd1; v[2] += xd0 * yd2;
        v[3] += xd1 * yd0; v[4] += xd1 * yd1; v[5] += xd1 * yd2;
        v[6] += xd2 * yd0; v[7] += xd2 * yd1; v[8] += xd2 * yd2;
        v[9]  += xd0 * xd0 + xd1 * xd1 + xd2 * xd2;
        v[10] += yd0 * yd0 + yd1 * yd1 + yd2 * yd2;
    }

    // 64-lane butterfly per wave.
    #pragma unroll
    for (int off = 32; off >= 1; off >>= 1) {
        #pragma unroll
        for (int i = 0; i < 11; ++i) v[i] += __shfl_xor(v[i], off, 64);
    }

    if ((t & 63) == 0) {
        #pragma unroll
        for (int i = 0; i < 11; ++i) red[t >> 6][i] = v[i];
    }
    __syncthreads();

    if (t < 11) {
        ws[(size_t)b * 12 + t] = red[0][t] + red[1][t] + red[2][t] + red[3][t];
    }
}

// ---------------- Kernel B: per-thread polar factor + epilogue ----------------
// One batch per thread; raw-rate v_rcp_f32 / v_sqrt_f32 (Newton iteration is
// self-correcting) keep the dependent critical path short.
__global__ __launch_bounds__(256) void polar_kernel(
    const float* __restrict__ ws,
    const float* __restrict__ mu_x, const float* __restrict__ mu_y,
    float* __restrict__ out)
{
    const int b = blockIdx.x * 256 + threadIdx.x;

    const float4* w4 = (const float4*)ws + 3 * (size_t)b;
    const float4 w0 = w4[0], w1 = w4[1], w2 = w4[2];

    float Q[9] = {w0.x, w0.y, w0.z, w0.w, w1.x, w1.y, w1.z, w1.w, w2.x};
    const float nxx = w2.y;   // |xc|^2
    const float nyy = w2.z;   // |yc|^2

    // Scaled Newton iteration for the orthogonal polar factor:
    //   Q <- 0.5 * (g*Q + (1/g) * Q^-T),  g = sqrt(||Q^-1||_F / ||Q||_F)
    #pragma unroll
    for (int it = 0; it < 11; ++it) {
        float C[9];
        C[0] = Q[4] * Q[8] - Q[5] * Q[7];
        C[1] = Q[5] * Q[6] - Q[3] * Q[8];
        C[2] = Q[3] * Q[7] - Q[4] * Q[6];
        C[3] = Q[2] * Q[7] - Q[1] * Q[8];
        C[4] = Q[0] * Q[8] - Q[2] * Q[6];
        C[5] = Q[1] * Q[6] - Q[0] * Q[7];
        C[6] = Q[1] * Q[5] - Q[2] * Q[4];
        C[7] = Q[2] * Q[3] - Q[0] * Q[5];
        C[8] = Q[0] * Q[4] - Q[1] * Q[3];
        const float det = Q[0] * C[0] + Q[1] * C[1] + Q[2] * C[2];
        const float invdet = __builtin_amdgcn_rcpf(det);

        float nq = 0.0f, nc = 0.0f;
        #pragma unroll
        for (int i = 0; i < 9; ++i) { nq += Q[i] * Q[i]; nc += C[i] * C[i]; }
        const float g  = __builtin_amdgcn_sqrtf(__builtin_amdgcn_sqrtf(
                             nc * invdet * invdet * __builtin_amdgcn_rcpf(nq)));
        const float hg = 0.5f * g;
        const float hi = 0.5f * invdet * __builtin_amdgcn_rcpf(g);
        #pragma unroll
        for (int i = 0; i < 9; ++i) Q[i] = hg * Q[i] + hi * C[i];
    }

    const float mx0 = mu_x[b * 3 + 0], mx1 = mu_x[b * 3 + 1], mx2 = mu_x[b * 3 + 2];
    const float my0 = mu_y[b * 3 + 0], my1 = mu_y[b * 3 + 1], my2 = mu_y[b * 3 + 2];

    #pragma unroll
    for (int i = 0; i < 9; ++i) out[(size_t)b * 9 + i] = Q[i];

    float* tout = out + (size_t)NB * 9 + (size_t)b * 3;
    tout[0] = my0 - (Q[0] * mx0 + Q[1] * mx1 + Q[2] * mx2);
    tout[1] = my1 - (Q[3] * mx0 + Q[4] * mx1 + Q[5] * mx2);
    tout[2] = my2 - (Q[6] * mx0 + Q[7] * mx1 + Q[8] * mx2);

    out[(size_t)NB * 12 + b] =
        __builtin_amdgcn_sqrtf(nyy) / (__builtin_amdgcn_sqrtf(nxx) + 1e-6f);
}

extern "C" void kernel_launch(void* const* d_in, const int* in_sizes, int n_in,
                              void* d_out, int out_size, void* d_ws, size_t ws_size,
                              hipStream_t stream) {
    const float* x    = (const float*)d_in[0];
    const float* mu_x = (const float*)d_in[1];
    const float* y    = (const float*)d_in[2];
    const float* mu_y = (const float*)d_in[3];
    float* out = (float*)d_out;
    float* ws  = (float*)d_ws;   // needs NB*12*4 = 384 KiB

    cov_kernel<<<dim3(NB), dim3(256), 0, stream>>>(x, y, mu_x, mu_y, ws);
    polar_kernel<<<dim3(NB / 256), dim3(256), 0, stream>>>(ws, mu_x, mu_y, out);
}